// Round 7
// baseline (187.260 us; speedup 1.0000x reference)
//
#include <hip/hip_runtime.h>
#include <stdint.h>

// MatrixKAN as dense bf16 MFMA GEMM over expanded interpolation basis.
// Per feature slots [0..20]=hat (2 nonzero), 21=silu(xc) (pairs base_w), 22..23=pad.
// K = 512*24 = 12288. Plane-major A tile in LDS; B fragments load directly from
// global Wt (slab layout == frag layout). bf16 split-K partials + reduce.
// R12: incremental A staging. R13: lgkmcnt-only barriers. R14: XCD swizzle.
// R16/R17 (REVERTED): per-wave register widening spills. R18 (REVERTED): W-pack
// "coalesced read" rewrite scattered the WRITES across 32 slabs/wave (+11us).
// R19: BN 128->64. R3/R6 counters: Occupancy 24.6% = 3 waves/SIMD (72 VGPR +
// 64 AGPR = 136 regs); MfmaUtil 48% = per-wave duty ~16%, TLP-starved (m114
// mechanism needs independent blocks to fill barrier stalls). Halve wave tile:
// acc[4][2]=32 AGPR, bv[3][2], ~100 regs -> 5 waves/SIMD, ~20 waves/CU, 1536
// blocks (~5/CU independent phases). Wt re-laid as 12KB slabs (64 rows); W-pack
// is old dense-write form, 1 block = 1 slab. P traffic x2 (+30MB, HBM at 13%).
// __launch_bounds__(256,4): cap 128 regs, NO spill risk (the R16/R17 killer).
// No fences (R7), no NT stores (R5).

typedef short v8s __attribute__((ext_vector_type(8)));
typedef float v4f __attribute__((ext_vector_type(4)));

#define B_DIM 8192
#define IN_DIM 512
#define OUT_DIM 512
#define G_DIM 20
#define FPT 4                        // features per K-tile
#define KT_TOTAL (IN_DIM / FPT)      // 128 K-tiles
#define KSPLIT 3
#define BM 128
#define BN 64
#define CHUNKS 12                    // 16B chunks per tile-row (3 per feature)
#define APLANE 2048                  // A: 128 rows * 16B per chunk-plane
#define ATILE_BYTES (CHUNKS * APLANE)   // 24 KB LDS A tile
#define WPLANE 1024                  // Wt: 64 rows * 16B per chunk-plane
#define TILE_BYTES (CHUNKS * WPLANE)    // 12 KB Wt slab

#define P_BYTES ((size_t)IN_DIM * B_DIM * 8)                          // 33.55 MB
#define WT_BYTES ((size_t)(OUT_DIM / BN) * KT_TOTAL * TILE_BYTES)     // 12.58 MB
#define PART_ELEMS ((size_t)B_DIM * OUT_DIM)
#define WS_NEED (P_BYTES + WT_BYTES + (size_t)KSPLIT * PART_ELEMS * 2)

#define PACK_BLKS ((B_DIM / 64) * (IN_DIM / 64))       // 1024
#define WPACK_BLKS ((OUT_DIM / BN) * KT_TOTAL)         // 1024: 1 block = 1 slab

static __device__ __forceinline__ unsigned f2bf(float f) {
  unsigned u = __builtin_bit_cast(unsigned, f);
  return (u + 0x7fffu + ((u >> 16) & 1u)) >> 16;   // RNE bf16
}

static __device__ __forceinline__ float bflo(unsigned u) {   // bf16 in low 16
  return __builtin_bit_cast(float, u << 16);
}
static __device__ __forceinline__ float bfhi(unsigned u) {   // bf16 in high 16
  return __builtin_bit_cast(float, u & 0xffff0000u);
}

// R13: lgkmcnt-only barrier. Drains LDS ops (staging ds_writes / prologue zero)
// but leaves global loads (B frags, P prefetch) in flight across the barrier.
// sched_barrier(0) on both sides per rule #18.
static __device__ __forceinline__ void lds_barrier() {
  __builtin_amdgcn_sched_barrier(0);
  asm volatile("s_waitcnt lgkmcnt(0)" ::: "memory");
  __builtin_amdgcn_s_barrier();
  __builtin_amdgcn_sched_barrier(0);
}

__global__ void zero_out_kernel(uint4* __restrict__ out) {
  out[(size_t)blockIdx.x * 256 + threadIdx.x] = uint4{0u, 0u, 0u, 0u};
}

// Fused input-pack. Blocks [0, PACK_BLKS): x[b][i] -> P[i][b] packed
// {.x = bf16(1-t)|bf16(t)<<16, .y = idx|bf16(silu)<<16} via LDS transpose.
// Blocks [PACK_BLKS, +WPACK_BLKS): coeffs/base_w -> Wt plane-major 12KB slabs.
// Block s = n_blk*128+kt; thread t: row=t>>2 (o=n_blk*64+row), f=t&3
// (i=kt*4+f). Reads: consecutive threads read consecutive 84B runs (wave =
// 5.4KB contiguous, L1-dense). Writes: 3 uint4/thread dense within ONE slab.
__global__ void pack_fused_kernel(const float* __restrict__ x, uint2* __restrict__ P,
                                  const float* __restrict__ coeffs,
                                  const float* __restrict__ base_w,
                                  char* __restrict__ Wt) {
  __shared__ uint2 tile[64 * 65];
  const int t = threadIdx.x;
  if (blockIdx.x < PACK_BLKS) {
    const int b0 = (blockIdx.x & (B_DIM / 64 - 1)) * 64;
    const int i0 = (blockIdx.x / (B_DIM / 64)) * 64;
    const int tr = t >> 6;
    const int tc = t & 63;
#pragma unroll
    for (int it = 0; it < 16; ++it) {
      int br = it * 4 + tr;
      float xv = x[(size_t)(b0 + br) * IN_DIM + i0 + tc];
      float xc = fminf(fmaxf(xv, -1.0f), 1.0f);
      float xg = (xc + 1.0f) * 10.0f;           // (xc+1)*0.5*G
      int idx = (int)floorf(xg);
      idx = idx < 0 ? 0 : (idx > G_DIM - 1 ? G_DIM - 1 : idx);
      float tt = xg - (float)idx;
      float sl = xc / (1.0f + __expf(-xc));     // silu(clipped x)
      uint2 pv;
      pv.x = f2bf(1.0f - tt) | (f2bf(tt) << 16);
      pv.y = (unsigned)idx | (f2bf(sl) << 16);
      tile[tc * 65 + br] = pv;
    }
    __syncthreads();
#pragma unroll
    for (int it = 0; it < 16; ++it) {
      int ir = it * 4 + tr;
      P[(size_t)(i0 + ir) * B_DIM + b0 + tc] = tile[ir * 65 + tc];
    }
  } else {
    const int s = blockIdx.x - PACK_BLKS;   // slab = n_blk*KT_TOTAL + kt
    const int n_blk = s >> 7;               // s / 128
    const int kt = s & 127;
    const int row = t >> 2;                 // o & 63
    const int f = t & 3;
    const int o = n_blk * BN + row;
    const int i = kt * 4 + f;
    const size_t g = (size_t)o * IN_DIM + i;
    const float* c = coeffs + g * 21;
    float cf[21];
#pragma unroll
    for (int j = 0; j < 21; ++j) cf[j] = c[j];
    float bw = base_w[g];
    unsigned d[12];
#pragma unroll
    for (int j = 0; j < 10; ++j) d[j] = f2bf(cf[2 * j]) | (f2bf(cf[2 * j + 1]) << 16);
    d[10] = f2bf(cf[20]) | (f2bf(bw) << 16);  // slots 20, 21(=base_w)
    d[11] = 0u;                               // slots 22,23 pad
    char* slab = Wt + (size_t)s * TILE_BYTES;
#pragma unroll
    for (int p = 0; p < 3; ++p)
      *(uint4*)(slab + (3 * f + p) * WPLANE + row * 16) =
          uint4{d[4 * p], d[4 * p + 1], d[4 * p + 2], d[4 * p + 3]};
  }
}

// out = p0+p1+p2: bf16 partial streams (8 per uint4), fp32 accumulate + store.
__global__ void reduce_kernel(const uint4* __restrict__ p, v4f* __restrict__ out) {
  size_t i = (size_t)blockIdx.x * 256 + threadIdx.x;
  const size_t q = PART_ELEMS / 8;
  uint4 a = p[i], b = p[i + q], c = p[i + 2 * q];
  v4f lo, hi;
  lo[0] = bflo(a.x) + bflo(b.x) + bflo(c.x);
  hi[0] = bfhi(a.x) + bfhi(b.x) + bfhi(c.x);
  lo[1] = bflo(a.y) + bflo(b.y) + bflo(c.y);
  hi[1] = bfhi(a.y) + bfhi(b.y) + bfhi(c.y);
  lo[2] = bflo(a.z) + bflo(b.z) + bflo(c.z);
  hi[2] = bfhi(a.z) + bfhi(b.z) + bfhi(c.z);
  lo[3] = bflo(a.w) + bflo(b.w) + bflo(c.w);
  hi[3] = bfhi(a.w) + bfhi(b.w) + bfhi(c.w);
  v4f o0 = {lo[0], hi[0], lo[1], hi[1]};
  v4f o1 = {lo[2], hi[2], lo[3], hi[3]};
  out[2 * i] = o0;
  out[2 * i + 1] = o1;
}

// slot -> byte offset within a lane's A-row slice (plane-major, APLANE)
static __device__ __forceinline__ int slot_off(int slot) {
  return ((slot >> 3) << 11) + ((slot & 7) << 1);   // plane*2048 + within-chunk
}

template <bool ATOMIC>
__global__ __launch_bounds__(256, 4) void kan_gemm(const uint2* __restrict__ P,
                                                   const char* __restrict__ Wt,
                                                   unsigned short* __restrict__ part,
                                                   float* __restrict__ outA) {
  __shared__ uint4 lds4[ATILE_BYTES / 16];   // 24KB A tile only (plane-major)
  char* Ab = (char*)lds4;
  const int t = threadIdx.x;
  const int lane = t & 63;
  const int wv = t >> 6;               // 4 waves, 2x2 grid of 64x32 tiles
  const int wm = wv >> 1, wn = wv & 1;

  // R14: XCD-aware chunked swizzle (bijective: 1536 = 192*8).
  const int L = blockIdx.x + ((blockIdx.y + (blockIdx.z << 3)) << 6);  // x + 64y + 512z
  const int nL = (L & 7) * 192 + (L >> 3);
  const int bx = nL & 63;
  const int by = (nL >> 6) & 7;
  const int bz = nL >> 9;

  const int b0 = bx * BM;
  const int n_blk = by;
  const int z = bz;
  const int kt0 = (z * KT_TOTAL) / KSPLIT;          // 0,42,85
  const int ktend = ((z + 1) * KT_TOTAL) / KSPLIT;  // 42,85,128

  v4f acc[4][2];
  const v4f z4 = {0.f, 0.f, 0.f, 0.f};
#pragma unroll
  for (int ii = 0; ii < 4; ++ii)
#pragma unroll
    for (int jj = 0; jj < 2; ++jj) acc[ii][jj] = z4;

  // prologue: zero the whole A tile once (1536 uint4 / 256 threads = 6 each)
  {
    const uint4 zz = {0u, 0u, 0u, 0u};
#pragma unroll
    for (int j = 0; j < 6; ++j) lds4[t + 256 * j] = zz;
  }

  // A-gen: wave wv owns feature wv (planes 3wv..3wv+2); lane owns rows lane, lane+64
  char* abase0 = Ab + 3 * wv * APLANE + lane * 16;
  char* abase1 = Ab + 3 * wv * APLANE + (lane + 64) * 16;
  uint2 pv0 = P[(size_t)(kt0 * 4 + wv) * B_DIM + b0 + lane];
  uint2 pv1 = P[(size_t)(kt0 * 4 + wv) * B_DIM + b0 + lane + 64];
  // cached clear addresses: init to current idx (clearing zeroed slots = no-op)
  char *c0a, *c0b, *c1a, *c1b;
  {
    int i0x = (int)(pv0.y & 0xffffu);
    c0a = abase0 + slot_off(i0x);
    c0b = abase0 + slot_off(i0x + 1);
    int i1x = (int)(pv1.y & 0xffffu);
    c1a = abase1 + slot_off(i1x);
    c1b = abase1 + slot_off(i1x + 1);
  }

  const int r16 = lane & 15;
  const int q16 = lane >> 4;

  // B frag global addresses: uint4 index chunk*64 + row (row = wn*32+cn*16+r16)
  const uint4* wbase = (const uint4*)(Wt + (size_t)n_blk * KT_TOTAL * TILE_BYTES);
  int bidx[3][2];
#pragma unroll
  for (int s = 0; s < 3; ++s)
#pragma unroll
    for (int cn = 0; cn < 2; ++cn)
      bidx[s][cn] = (s * 4 + q16) * 64 + wn * 32 + cn * 16 + r16;

  for (int kt = kt0; kt < ktend; ++kt) {
    // barrier 1: previous compute done (all ds_reads consumed before MFMA issue;
    // lgkmcnt(0) additionally drains the prologue zero on iter 0). No vmcnt drain.
    lds_barrier();

    // B frags for this kt: 6x buffer_load_dwordx4 straight from L1/L2
    const uint4* wsrc = wbase + (size_t)kt * (TILE_BYTES / 16);
    uint4 bv[3][2];
#pragma unroll
    for (int s = 0; s < 3; ++s)
#pragma unroll
      for (int cn = 0; cn < 2; ++cn)
        bv[s][cn] = wsrc[bidx[s][cn]];

    // prefetch next P (in flight across barrier + compute)
    const int ktn = (kt + 1 < ktend) ? kt + 1 : kt;
    uint2 pn0 = P[(size_t)(ktn * 4 + wv) * B_DIM + b0 + lane];
    uint2 pn1 = P[(size_t)(ktn * 4 + wv) * B_DIM + b0 + lane + 64];

    // incremental A stage: clear previous hat slots, write new w0/w1/silu
    {
      *(unsigned short*)c0a = 0;
      *(unsigned short*)c0b = 0;
      int idx = (int)(pv0.y & 0xffffu);
      char* wa = abase0 + slot_off(idx);
      char* wb = abase0 + slot_off(idx + 1);
      *(unsigned short*)wa = (unsigned short)pv0.x;
      *(unsigned short*)wb = (unsigned short)(pv0.x >> 16);
      *(unsigned short*)(abase0 + 2 * APLANE + 10) = (unsigned short)(pv0.y >> 16);
      c0a = wa; c0b = wb;
    }
    {
      *(unsigned short*)c1a = 0;
      *(unsigned short*)c1b = 0;
      int idx = (int)(pv1.y & 0xffffu);
      char* wa = abase1 + slot_off(idx);
      char* wb = abase1 + slot_off(idx + 1);
      *(unsigned short*)wa = (unsigned short)pv1.x;
      *(unsigned short*)wb = (unsigned short)(pv1.x >> 16);
      *(unsigned short*)(abase1 + 2 * APLANE + 10) = (unsigned short)(pv1.y >> 16);
      c1a = wa; c1b = wb;
    }
    pv0 = pn0;
    pv1 = pn1;

    // barrier 2: A ds_writes visible to all waves (lgkmcnt(0) only). B/P global
    // loads stay in flight; compiler waits vmcnt at first bv use inside compute.
    lds_barrier();

    // compute: 3 K32-steps, 8 MFMA each per wave; A from LDS, B from regs
#pragma unroll
    for (int s = 0; s < 3; ++s) {
      const int chunk = s * 4 + q16;   // plane index; k = chunk*8 + j
      v8s af[4];
#pragma unroll
      for (int rm = 0; rm < 4; ++rm) {
        int row = wm * 64 + rm * 16 + r16;
        af[rm] = *(const v8s*)(Ab + chunk * APLANE + row * 16);
      }
#pragma unroll
      for (int rm = 0; rm < 4; ++rm)
#pragma unroll
        for (int cn = 0; cn < 2; ++cn)
          acc[rm][cn] = __builtin_amdgcn_mfma_f32_16x16x32_bf16(
              af[rm], __builtin_bit_cast(v8s, bv[s][cn]), acc[rm][cn], 0, 0, 0);
    }
  }

  // epilogue: C/D layout col=lane&15, row=(lane>>4)*4+reg (verified m89/m91)
  const int q4 = (lane >> 4) * 4;
  if (ATOMIC) {
#pragma unroll
    for (int rm = 0; rm < 4; ++rm)
#pragma unroll
      for (int cn = 0; cn < 2; ++cn)
#pragma unroll
        for (int r = 0; r < 4; ++r) {
          int row = b0 + wm * 64 + rm * 16 + q4 + r;
          int col = n_blk * BN + wn * 32 + cn * 16 + r16;
          atomicAdd(outA + (size_t)row * OUT_DIM + col, acc[rm][cn][r]);
        }
  } else {
    // bf16 partials: half the split-K write traffic; reduce re-expands to fp32
    unsigned short* mypart = part + (size_t)z * PART_ELEMS;
#pragma unroll
    for (int rm = 0; rm < 4; ++rm)
#pragma unroll
      for (int cn = 0; cn < 2; ++cn)
#pragma unroll
        for (int r = 0; r < 4; ++r) {
          int row = b0 + wm * 64 + rm * 16 + q4 + r;
          int col = n_blk * BN + wn * 32 + cn * 16 + r16;
          mypart[(size_t)row * OUT_DIM + col] = (unsigned short)f2bf(acc[rm][cn][r]);
        }
  }
}

extern "C" void kernel_launch(void* const* d_in, const int* in_sizes, int n_in,
                              void* d_out, int out_size, void* d_ws, size_t ws_size,
                              hipStream_t stream) {
  const float* x = (const float*)d_in[0];
  const float* coeffs = (const float*)d_in[1];
  const float* base_w = (const float*)d_in[2];
  float* out = (float*)d_out;

  uint2* P = (uint2*)d_ws;
  char* Wt = (char*)d_ws + P_BYTES;
  unsigned short* part = (unsigned short*)((char*)d_ws + P_BYTES + WT_BYTES);

  pack_fused_kernel<<<PACK_BLKS + WPACK_BLKS, 256, 0, stream>>>(x, P, coeffs, base_w, Wt);

  if (ws_size >= WS_NEED) {
    kan_gemm<false><<<dim3(B_DIM / BM, OUT_DIM / BN, KSPLIT), 256, 0, stream>>>(P, Wt, part, out);
    reduce_kernel<<<(int)(PART_ELEMS / 8 / 256), 256, 0, stream>>>((const uint4*)part, (v4f*)out);
  } else {
    zero_out_kernel<<<(int)((PART_ELEMS * 4) / 4096), 256, 0, stream>>>((uint4*)out);
    kan_gemm<true><<<dim3(B_DIM / BM, OUT_DIM / BN, KSPLIT), 256, 0, stream>>>(P, Wt, part, out);
  }
}

// Round 8
// 179.341 us; speedup vs baseline: 1.0442x; 1.0442x over previous
//
#include <hip/hip_runtime.h>
#include <stdint.h>

// MatrixKAN as dense bf16 MFMA GEMM over expanded interpolation basis.
// Per feature slots [0..20]=hat (2 nonzero), 21=silu(xc) (pairs base_w), 22..23=pad.
// K = 512*24 = 12288. Plane-major A tile in LDS; B fragments from global Wt
// (slab layout == frag layout, L2-served). KSPLIT=3: 768 blocks = 3/CU.
// R12: incremental A staging. R13: lgkmcnt-only barriers. R14: XCD swizzle.
// R16/R17 (REVERTED): register widening -> scratch spill. R18 (REVERTED):
// W-pack rewrite scattered writes. R19 (REVERTED): BN=64 raised occupancy
// 24.6->37% but MfmaUtil FELL 48->43 (per-MFMA overhead doubled) -- occupancy
// was not the binding constraint.
// R20: A-tile DOUBLE-BUFFER, one barrier/iter. R3 cycle model: MFMA 2794 +
// LDS 1776 = 88% of the 5170-cyc wall -- the 2-barrier lockstep serializes the
// ds_read burst against MFMA. With dbuf, compute reads buf[rd] (staged last
// iter) while staging writes buf[stg]; single end-of-iter barrier; stage/
// ds_read/MFMA/B-loads share one scheduling region so the LDS and matrix pipes
// overlap across the 12 waves/CU. Pointer ping-pong via named swaps (rule #20:
// no runtime-indexed arrays; +~8 VGPR only). T5 setprio(1) around MFMA
// clusters (waves now role-diverse within the region).
// No fences (R7), no NT stores (R5).

typedef short v8s __attribute__((ext_vector_type(8)));
typedef float v4f __attribute__((ext_vector_type(4)));

#define B_DIM 8192
#define IN_DIM 512
#define OUT_DIM 512
#define G_DIM 20
#define FPT 4                        // features per K-tile
#define KT_TOTAL (IN_DIM / FPT)      // 128 K-tiles
#define KSPLIT 3
#define BM 128
#define BN 128
#define CHUNKS 12                    // 16B chunks per tile-row (3 per feature)
#define PLANE 2048                   // 128 rows * 16B per chunk-plane
#define TILE_BYTES (CHUNKS * PLANE)  // 24 KB per buffer

#define P_BYTES ((size_t)IN_DIM * B_DIM * 8)                          // 33.55 MB
#define WT_BYTES ((size_t)(OUT_DIM / BN) * KT_TOTAL * TILE_BYTES)     // 12.58 MB
#define PART_ELEMS ((size_t)B_DIM * OUT_DIM)
#define WS_NEED (P_BYTES + WT_BYTES + (size_t)KSPLIT * PART_ELEMS * 2)

#define PACK_BLKS ((B_DIM / 64) * (IN_DIM / 64))   // 1024
#define WPACK_BLKS ((OUT_DIM * IN_DIM) / 256)      // 1024

static __device__ __forceinline__ unsigned f2bf(float f) {
  unsigned u = __builtin_bit_cast(unsigned, f);
  return (u + 0x7fffu + ((u >> 16) & 1u)) >> 16;   // RNE bf16
}

static __device__ __forceinline__ float bflo(unsigned u) {   // bf16 in low 16
  return __builtin_bit_cast(float, u << 16);
}
static __device__ __forceinline__ float bfhi(unsigned u) {   // bf16 in high 16
  return __builtin_bit_cast(float, u & 0xffff0000u);
}

// R13: lgkmcnt-only barrier. Drains LDS ops (staging ds_writes / prologue zero)
// but leaves global loads (B frags, P prefetch) in flight across the barrier.
// sched_barrier(0) on both sides per rule #18.
static __device__ __forceinline__ void lds_barrier() {
  __builtin_amdgcn_sched_barrier(0);
  asm volatile("s_waitcnt lgkmcnt(0)" ::: "memory");
  __builtin_amdgcn_s_barrier();
  __builtin_amdgcn_sched_barrier(0);
}

__global__ void zero_out_kernel(uint4* __restrict__ out) {
  out[(size_t)blockIdx.x * 256 + threadIdx.x] = uint4{0u, 0u, 0u, 0u};
}

// Fused input-pack. Blocks [0, PACK_BLKS): x[b][i] -> P[i][b] packed
// {.x = bf16(1-t)|bf16(t)<<16, .y = idx|bf16(silu)<<16} via LDS transpose.
// Blocks [PACK_BLKS, +WPACK_BLKS): coeffs/base_w -> Wt plane-major 24KB slabs
// (slab (n_blk,kt): plane 3f+cf = slots 8cf..8cf+7 of feature kt*4+f, row=o&127).
__global__ void pack_fused_kernel(const float* __restrict__ x, uint2* __restrict__ P,
                                  const float* __restrict__ coeffs,
                                  const float* __restrict__ base_w,
                                  char* __restrict__ Wt) {
  __shared__ uint2 tile[64 * 65];
  const int t = threadIdx.x;
  if (blockIdx.x < PACK_BLKS) {
    const int b0 = (blockIdx.x & (B_DIM / 64 - 1)) * 64;
    const int i0 = (blockIdx.x / (B_DIM / 64)) * 64;
    const int tr = t >> 6;
    const int tc = t & 63;
#pragma unroll
    for (int it = 0; it < 16; ++it) {
      int br = it * 4 + tr;
      float xv = x[(size_t)(b0 + br) * IN_DIM + i0 + tc];
      float xc = fminf(fmaxf(xv, -1.0f), 1.0f);
      float xg = (xc + 1.0f) * 10.0f;           // (xc+1)*0.5*G
      int idx = (int)floorf(xg);
      idx = idx < 0 ? 0 : (idx > G_DIM - 1 ? G_DIM - 1 : idx);
      float tt = xg - (float)idx;
      float sl = xc / (1.0f + __expf(-xc));     // silu(clipped x)
      uint2 pv;
      pv.x = f2bf(1.0f - tt) | (f2bf(tt) << 16);
      pv.y = (unsigned)idx | (f2bf(sl) << 16);
      tile[tc * 65 + br] = pv;
    }
    __syncthreads();
#pragma unroll
    for (int it = 0; it < 16; ++it) {
      int ir = it * 4 + tr;
      P[(size_t)(i0 + ir) * B_DIM + b0 + tc] = tile[ir * 65 + tc];
    }
  } else {
    const unsigned u = (blockIdx.x - PACK_BLKS) * 256 + t;
    const int s = u >> 9;            // slab = n_blk*KT_TOTAL + kt
    const int w = u & 511;
    const int row = w >> 2;          // o & 127
    const int f = w & 3;
    const int n_blk = s / KT_TOTAL;
    const int kt = s - n_blk * KT_TOTAL;
    const int o = n_blk * 128 + row;
    const int i = kt * 4 + f;
    const size_t g = (size_t)o * IN_DIM + i;
    const float* c = coeffs + g * 21;
    float cf[21];
#pragma unroll
    for (int j = 0; j < 21; ++j) cf[j] = c[j];
    float bw = base_w[g];
    unsigned d[12];
#pragma unroll
    for (int j = 0; j < 10; ++j) d[j] = f2bf(cf[2 * j]) | (f2bf(cf[2 * j + 1]) << 16);
    d[10] = f2bf(cf[20]) | (f2bf(bw) << 16);  // slots 20, 21(=base_w)
    d[11] = 0u;                               // slots 22,23 pad
    char* slab = Wt + (size_t)s * TILE_BYTES;
#pragma unroll
    for (int p = 0; p < 3; ++p)
      *(uint4*)(slab + (3 * f + p) * PLANE + row * 16) =
          uint4{d[4 * p], d[4 * p + 1], d[4 * p + 2], d[4 * p + 3]};
  }
}

// out = p0+p1+p2: bf16 partial streams (8 per uint4), fp32 accumulate + store.
__global__ void reduce_kernel(const uint4* __restrict__ p, v4f* __restrict__ out) {
  size_t i = (size_t)blockIdx.x * 256 + threadIdx.x;
  const size_t q = PART_ELEMS / 8;
  uint4 a = p[i], b = p[i + q], c = p[i + 2 * q];
  v4f lo, hi;
  lo[0] = bflo(a.x) + bflo(b.x) + bflo(c.x);
  hi[0] = bfhi(a.x) + bfhi(b.x) + bfhi(c.x);
  lo[1] = bflo(a.y) + bflo(b.y) + bflo(c.y);
  hi[1] = bfhi(a.y) + bfhi(b.y) + bfhi(c.y);
  lo[2] = bflo(a.z) + bflo(b.z) + bflo(c.z);
  hi[2] = bfhi(a.z) + bfhi(b.z) + bfhi(c.z);
  lo[3] = bflo(a.w) + bflo(b.w) + bflo(c.w);
  hi[3] = bfhi(a.w) + bfhi(b.w) + bfhi(c.w);
  v4f o0 = {lo[0], hi[0], lo[1], hi[1]};
  v4f o1 = {lo[2], hi[2], lo[3], hi[3]};
  out[2 * i] = o0;
  out[2 * i + 1] = o1;
}

// slot -> byte offset within a lane's row slice (plane-major)
static __device__ __forceinline__ int slot_off(int slot) {
  return ((slot >> 3) << 11) + ((slot & 7) << 1);   // plane*2048 + within-chunk
}

template <bool ATOMIC>
__global__ __launch_bounds__(256, 3) void kan_gemm(const uint2* __restrict__ P,
                                                   const char* __restrict__ Wt,
                                                   unsigned short* __restrict__ part,
                                                   float* __restrict__ outA) {
  __shared__ uint4 lds4[2 * TILE_BYTES / 16];   // 48KB: double-buffered A tile
  char* Ab = (char*)lds4;
  const int t = threadIdx.x;
  const int lane = t & 63;
  const int wv = t >> 6;               // 4 waves, 2x2 grid of 64x64 tiles
  const int wm = wv >> 1, wn = wv & 1;

  // R14: XCD-aware chunked swizzle (bijective: 768 = 96*8).
  const int L = blockIdx.x + ((blockIdx.y + (blockIdx.z << 2)) << 6);  // x + 64y + 256z
  const int nL = (L & 7) * 96 + (L >> 3);
  const int bx = nL & 63;
  const int by = (nL >> 6) & 3;
  const int bz = nL >> 8;

  const int b0 = bx * BM;
  const int n_blk = by;
  const int z = bz;
  const int kt0 = (z * KT_TOTAL) / KSPLIT;          // 0,42,85
  const int ktend = ((z + 1) * KT_TOTAL) / KSPLIT;  // 42,85,128

  v4f acc[4][4];
  const v4f z4 = {0.f, 0.f, 0.f, 0.f};
#pragma unroll
  for (int ii = 0; ii < 4; ++ii)
#pragma unroll
    for (int jj = 0; jj < 4; ++jj) acc[ii][jj] = z4;

  // prologue: zero BOTH buffers once (3072 uint4 / 256 threads = 12 each)
  {
    const uint4 zz = {0u, 0u, 0u, 0u};
#pragma unroll
    for (int j = 0; j < 12; ++j) lds4[t + 256 * j] = zz;
  }

  // A-gen: wave wv owns feature wv (planes 3wv..3wv+2); lane owns rows lane,
  // lane+64. Per-lane row byte offsets within a buffer:
  const int ro0 = 3 * wv * PLANE + lane * 16;
  const int ro1 = 3 * wv * PLANE + (lane + 64) * 16;

  // dbuf pointers: stg = buffer being staged this step, rd = buffer being read.
  char* stg = Ab;                 // prologue stages kt0 into buf0
  char* rd = Ab + TILE_BYTES;

  uint2 pv0 = P[(size_t)(kt0 * 4 + wv) * B_DIM + b0 + lane];
  uint2 pv1 = P[(size_t)(kt0 * 4 + wv) * B_DIM + b0 + lane + 64];

  // clear-address sets: cc* = for the buffer staged THIS step (init: no-op
  // clears of the slots about to be written in buf0); ca* = for the other
  // buffer's first staging (slots 0/1 in buf1: zeroed, never written = no-op).
  char *cc0a, *cc0b, *cc1a, *cc1b, *ca0a, *ca0b, *ca1a, *ca1b;
  {
    int i0x = (int)(pv0.y & 0xffffu);
    cc0a = stg + ro0 + slot_off(i0x);
    cc0b = stg + ro0 + slot_off(i0x + 1);
    int i1x = (int)(pv1.y & 0xffffu);
    cc1a = stg + ro1 + slot_off(i1x);
    cc1b = stg + ro1 + slot_off(i1x + 1);
    ca0a = rd + ro0 + slot_off(0);
    ca0b = rd + ro0 + slot_off(1);
    ca1a = rd + ro1 + slot_off(0);
    ca1b = rd + ro1 + slot_off(1);
  }

  const int r16 = lane & 15;
  const int q16 = lane >> 4;

  // B frag global addresses: uint4 index chunk*128 + row (row = wn*64+cn*16+r16)
  const uint4* wbase = (const uint4*)(Wt + (size_t)n_blk * KT_TOTAL * TILE_BYTES);
  int bidx[3][4];
#pragma unroll
  for (int s = 0; s < 3; ++s)
#pragma unroll
    for (int cn = 0; cn < 4; ++cn)
      bidx[s][cn] = (s * 4 + q16) * 128 + wn * 64 + cn * 16 + r16;

  // STAGE: write features of K-tile (pv holds their P-values) into stg; clear
  // the slots written 2 stagings ago in stg; prefetch P for the next staging.
#define STAGE(ktnext_clamped)                                                   \
  {                                                                             \
    uint2 pn0 = P[(size_t)((ktnext_clamped) * 4 + wv) * B_DIM + b0 + lane];     \
    uint2 pn1 = P[(size_t)((ktnext_clamped) * 4 + wv) * B_DIM + b0 + lane + 64];\
    *(unsigned short*)cc0a = 0;                                                 \
    *(unsigned short*)cc0b = 0;                                                 \
    {                                                                           \
      int idx = (int)(pv0.y & 0xffffu);                                         \
      char* wa = stg + ro0 + slot_off(idx);                                     \
      char* wb = stg + ro0 + slot_off(idx + 1);                                 \
      *(unsigned short*)wa = (unsigned short)pv0.x;                             \
      *(unsigned short*)wb = (unsigned short)(pv0.x >> 16);                     \
      *(unsigned short*)(stg + ro0 + 2 * PLANE + 10) =                          \
          (unsigned short)(pv0.y >> 16);                                        \
      cc0a = wa; cc0b = wb;                                                     \
    }                                                                           \
    *(unsigned short*)cc1a = 0;                                                 \
    *(unsigned short*)cc1b = 0;                                                 \
    {                                                                           \
      int idx = (int)(pv1.y & 0xffffu);                                         \
      char* wa = stg + ro1 + slot_off(idx);                                     \
      char* wb = stg + ro1 + slot_off(idx + 1);                                 \
      *(unsigned short*)wa = (unsigned short)pv1.x;                             \
      *(unsigned short*)wb = (unsigned short)(pv1.x >> 16);                     \
      *(unsigned short*)(stg + ro1 + 2 * PLANE + 10) =                          \
          (unsigned short)(pv1.y >> 16);                                        \
      cc1a = wa; cc1b = wb;                                                     \
    }                                                                           \
    pv0 = pn0;                                                                  \
    pv1 = pn1;                                                                  \
  }

#define SWAPP(a, b) { char* _tmp = a; a = b; b = _tmp; }
#define SWAP_BUFS()                                                             \
  {                                                                             \
    SWAPP(stg, rd);                                                             \
    SWAPP(cc0a, ca0a); SWAPP(cc0b, ca0b);                                       \
    SWAPP(cc1a, ca1a); SWAPP(cc1b, ca1b);                                       \
  }

  // prologue: zero visible -> stage kt0 into buf0 -> visible -> loop
  lds_barrier();
  STAGE(kt0 + 1 < ktend ? kt0 + 1 : kt0);   // writes kt0 data; pv -> kt0+1
  SWAP_BUFS();                              // rd = buf0 (kt0), stg = buf1
  lds_barrier();

  for (int kt = kt0; kt < ktend; ++kt) {
    // Single scheduling region: B loads + staging(kt+1 -> stg) + ds_reads(rd)
    // + MFMA all interleave; one barrier at the end.
    const uint4* wsrc = wbase + (size_t)kt * (TILE_BYTES / 16);
    uint4 bv[3][4];
#pragma unroll
    for (int s = 0; s < 3; ++s)
#pragma unroll
      for (int cn = 0; cn < 4; ++cn)
        bv[s][cn] = wsrc[bidx[s][cn]];

    if (kt + 1 < ktend) {
      STAGE(kt + 2 < ktend ? kt + 2 : kt + 1);  // stage kt+1; pv -> kt+2
    }

    // compute from rd: 3 K32-steps, 16 MFMA each per wave
#pragma unroll
    for (int s = 0; s < 3; ++s) {
      const int chunk = s * 4 + q16;   // plane index; k = chunk*8 + j
      v8s af[4];
#pragma unroll
      for (int rm = 0; rm < 4; ++rm) {
        int row = wm * 64 + rm * 16 + r16;
        af[rm] = *(const v8s*)(rd + chunk * PLANE + row * 16);
      }
      __builtin_amdgcn_s_setprio(1);
#pragma unroll
      for (int rm = 0; rm < 4; ++rm)
#pragma unroll
        for (int cn = 0; cn < 4; ++cn)
          acc[rm][cn] = __builtin_amdgcn_mfma_f32_16x16x32_bf16(
              af[rm], __builtin_bit_cast(v8s, bv[s][cn]), acc[rm][cn], 0, 0, 0);
      __builtin_amdgcn_s_setprio(0);
    }

    // end-of-iter: drain staging ds_writes, make stg visible; then swap roles.
    lds_barrier();
    SWAP_BUFS();
  }
#undef STAGE
#undef SWAPP
#undef SWAP_BUFS

  // epilogue: C/D layout col=lane&15, row=(lane>>4)*4+reg (verified m89/m91)
  const int q4 = (lane >> 4) * 4;
  if (ATOMIC) {
#pragma unroll
    for (int rm = 0; rm < 4; ++rm)
#pragma unroll
      for (int cn = 0; cn < 4; ++cn)
#pragma unroll
        for (int r = 0; r < 4; ++r) {
          int row = b0 + wm * 64 + rm * 16 + q4 + r;
          int col = n_blk * BN + wn * 64 + cn * 16 + r16;
          atomicAdd(outA + (size_t)row * OUT_DIM + col, acc[rm][cn][r]);
        }
  } else {
    // bf16 partials: half the split-K write traffic; reduce re-expands to fp32
    unsigned short* mypart = part + (size_t)z * PART_ELEMS;
#pragma unroll
    for (int rm = 0; rm < 4; ++rm)
#pragma unroll
      for (int cn = 0; cn < 4; ++cn)
#pragma unroll
        for (int r = 0; r < 4; ++r) {
          int row = b0 + wm * 64 + rm * 16 + q4 + r;
          int col = n_blk * BN + wn * 64 + cn * 16 + r16;
          mypart[(size_t)row * OUT_DIM + col] = (unsigned short)f2bf(acc[rm][cn][r]);
        }
  }
}

extern "C" void kernel_launch(void* const* d_in, const int* in_sizes, int n_in,
                              void* d_out, int out_size, void* d_ws, size_t ws_size,
                              hipStream_t stream) {
  const float* x = (const float*)d_in[0];
  const float* coeffs = (const float*)d_in[1];
  const float* base_w = (const float*)d_in[2];
  float* out = (float*)d_out;

  uint2* P = (uint2*)d_ws;
  char* Wt = (char*)d_ws + P_BYTES;
  unsigned short* part = (unsigned short*)((char*)d_ws + P_BYTES + WT_BYTES);

  pack_fused_kernel<<<PACK_BLKS + WPACK_BLKS, 256, 0, stream>>>(x, P, coeffs, base_w, Wt);

  if (ws_size >= WS_NEED) {
    kan_gemm<false><<<dim3(B_DIM / BM, OUT_DIM / BN, KSPLIT), 256, 0, stream>>>(P, Wt, part, out);
    reduce_kernel<<<(int)(PART_ELEMS / 8 / 256), 256, 0, stream>>>((const uint4*)part, (v4f*)out);
  } else {
    zero_out_kernel<<<(int)((PART_ELEMS * 4) / 4096), 256, 0, stream>>>((uint4*)out);
    kan_gemm<true><<<dim3(B_DIM / BM, OUT_DIM / BN, KSPLIT), 256, 0, stream>>>(P, Wt, part, out);
  }
}